// Round 1
// baseline (614.650 us; speedup 1.0000x reference)
//
#include <hip/hip_runtime.h>
#include <hip/hip_bf16.h>

#define D_MODEL 1024
#define NHEAD   16
#define DH      64
#define BATCH   4
#define SEQ     2048

typedef __bf16 bf16;
typedef __bf16 bf16x8 __attribute__((ext_vector_type(8)));
typedef __bf16 bf16x4 __attribute__((ext_vector_type(4)));
typedef float  f32x4  __attribute__((ext_vector_type(4)));

// ---------------- weight transpose + convert: Wt[n][k] = (bf16) W[k][n] ----------------
__global__ __launch_bounds__(256) void wt_kernel(const float* __restrict__ W,
                                                 bf16* __restrict__ Wt) {
    __shared__ float t[32][33];
    int x = threadIdx.x, y = threadIdx.y;          // block (32,8)
    int bi = blockIdx.x * 32;                      // k rows
    int bj = blockIdx.y * 32;                      // n cols
#pragma unroll
    for (int j = 0; j < 4; ++j)
        t[y + j * 8][x] = W[(bi + y + j * 8) * D_MODEL + bj + x];
    __syncthreads();
#pragma unroll
    for (int j = 0; j < 4; ++j)
        Wt[(long long)(bj + y + j * 8) * D_MODEL + bi + x] = (bf16)t[x][y + j * 8];
}

// ---------------- mask pack: bits[b][q][kv/32], bit = (mask != 0) ----------------
__global__ __launch_bounds__(256) void maskpack_kernel(const int* __restrict__ mask,
                                                       unsigned* __restrict__ bits) {
    long long tid = (long long)blockIdx.x * 256 + threadIdx.x;
    int lane = threadIdx.x & 63;
    long long wid = tid >> 6;
    int m = mask[wid * 64 + lane];
    unsigned long long bal = __ballot(m != 0);
    if (lane == 0) *(unsigned long long*)&bits[wid * 2] = bal;
}

// ---------------- GEMM: C[M,N] = A[M,K] @ Bt[N,K]^T + bias ----------------
// A_IS_BF16=false: A fp32 (converted in staging). OUT_MODE: 0 -> bf16 [B,H,S,Dh],
// 1 -> bf16 [B,H,Dh,S], 2 -> fp32 [M,N].
template <bool A_IS_BF16, int OUT_MODE>
__global__ __launch_bounds__(256) void gemm_kernel(const void* __restrict__ Aptr,
                                                   const bf16* __restrict__ Bt,
                                                   const float* __restrict__ bias,
                                                   void* __restrict__ Cptr) {
    constexpr int K = D_MODEL;
    __shared__ bf16 As[128][40];
    __shared__ bf16 Bs[128][40];
    int tid = threadIdx.x;
    int l = tid & 63, w = tid >> 6;
    int g = l >> 4, c = l & 15;
    int wm = (w >> 1) * 64, wn = (w & 1) * 64;
    long long m0 = (long long)blockIdx.y * 128;
    int n0 = blockIdx.x * 128;

    f32x4 acc[4][4] = {};

    for (int k0 = 0; k0 < K; k0 += 32) {
        if constexpr (!A_IS_BF16) {
            const float* A = (const float*)Aptr;
            int row = tid >> 3, cc = (tid & 7) * 4;
#pragma unroll
            for (int i = 0; i < 4; ++i) {
                float4 v = *(const float4*)&A[(m0 + row + i * 32) * K + k0 + cc];
                bf16x4 hh;
                hh[0] = (bf16)v.x; hh[1] = (bf16)v.y; hh[2] = (bf16)v.z; hh[3] = (bf16)v.w;
                *(bf16x4*)&As[row + i * 32][cc] = hh;
            }
        } else {
            const bf16* A = (const bf16*)Aptr;
            int row = tid >> 2, cc = (tid & 3) * 8;
#pragma unroll
            for (int i = 0; i < 2; ++i)
                *(bf16x8*)&As[row + i * 64][cc] =
                    *(const bf16x8*)&A[(m0 + row + i * 64) * K + k0 + cc];
        }
        {
            int row = tid >> 2, cc = (tid & 3) * 8;
#pragma unroll
            for (int i = 0; i < 2; ++i)
                *(bf16x8*)&Bs[row + i * 64][cc] =
                    *(const bf16x8*)&Bt[(long long)(n0 + row + i * 64) * K + k0 + cc];
        }
        __syncthreads();
        bf16x8 af[4], bfr[4];
#pragma unroll
        for (int i = 0; i < 4; ++i) af[i] = *(const bf16x8*)&As[wm + i * 16 + c][g * 8];
#pragma unroll
        for (int i = 0; i < 4; ++i) bfr[i] = *(const bf16x8*)&Bs[wn + i * 16 + c][g * 8];
#pragma unroll
        for (int mi = 0; mi < 4; ++mi)
#pragma unroll
            for (int ni = 0; ni < 4; ++ni)
                acc[mi][ni] = __builtin_amdgcn_mfma_f32_16x16x32_bf16(af[mi], bfr[ni],
                                                                     acc[mi][ni], 0, 0, 0);
        __syncthreads();
    }

#pragma unroll
    for (int mi = 0; mi < 4; ++mi) {
#pragma unroll
        for (int ni = 0; ni < 4; ++ni) {
            int n = n0 + wn + ni * 16 + c;
            float bv = bias[n];
#pragma unroll
            for (int r = 0; r < 4; ++r) {
                long long m = m0 + wm + mi * 16 + g * 4 + r;
                float val = acc[mi][ni][r] + bv;
                if constexpr (OUT_MODE == 2) {
                    ((float*)Cptr)[m * D_MODEL + n] = val;
                } else {
                    int b = (int)(m >> 11), s = (int)(m & 2047);
                    int h = n >> 6, f = n & 63;
                    long long addr;
                    if constexpr (OUT_MODE == 0)
                        addr = ((long long)(b * NHEAD + h) * SEQ + s) * DH + f;
                    else
                        addr = ((long long)(b * NHEAD + h) * DH + f) * SEQ + s;
                    ((bf16*)Cptr)[addr] = (bf16)val;
                }
            }
        }
    }
}

// ---------------- flash attention ----------------
// Q,Kt: [BH][S][DH] bf16; Vt: [BH][DH][S] bf16; bits: packed mask; O: [B][S][D_MODEL] bf16
__global__ __launch_bounds__(256) void attn_kernel(const bf16* __restrict__ Q,
                                                   const bf16* __restrict__ Kt,
                                                   const bf16* __restrict__ Vt,
                                                   const unsigned* __restrict__ bits,
                                                   bf16* __restrict__ O) {
    __shared__ bf16 Ks[64][72];
    __shared__ bf16 Vs[64][72];
    __shared__ bf16 Ps[4][16][72];
    int tid = threadIdx.x;
    int l = tid & 63, w = tid >> 6;
    int g = l >> 4, c = l & 15;
    int bh = blockIdx.y;
    int b = bh >> 4, h = bh & 15;
    int q0 = blockIdx.x * 64;

    bf16x8 qf[2];
    {
        long long base = ((long long)bh * SEQ + q0 + w * 16 + c) * DH + g * 8;
        qf[0] = *(const bf16x8*)&Q[base];
        qf[1] = *(const bf16x8*)&Q[base + 32];
    }

    f32x4 o_acc[4] = {};
    float m_run[4], l_run[4];
#pragma unroll
    for (int r = 0; r < 4; ++r) { m_run[r] = -INFINITY; l_run[r] = 0.f; }

    const long long kbase = (long long)bh * SEQ * DH;
    const long long vbase = (long long)bh * DH * SEQ;

    for (int kv0 = 0; kv0 < SEQ; kv0 += 64) {
#pragma unroll
        for (int i = 0; i < 2; ++i) {
            int ch = tid + i * 256;
            int row = ch >> 3, cc = (ch & 7) * 8;
            *(bf16x8*)&Ks[row][cc] =
                *(const bf16x8*)&Kt[kbase + (long long)(kv0 + row) * DH + cc];
            *(bf16x8*)&Vs[row][cc] =
                *(const bf16x8*)&Vt[vbase + (long long)row * SEQ + kv0 + cc];
        }
        __syncthreads();

        // S = Q K^T   (D: row = g*4+r (q), col = c (kv))
        f32x4 sacc[4] = {};
#pragma unroll
        for (int nb = 0; nb < 4; ++nb) {
            bf16x8 k0f = *(const bf16x8*)&Ks[nb * 16 + c][g * 8];
            bf16x8 k1f = *(const bf16x8*)&Ks[nb * 16 + c][32 + g * 8];
            sacc[nb] = __builtin_amdgcn_mfma_f32_16x16x32_bf16(qf[0], k0f, sacc[nb], 0, 0, 0);
            sacc[nb] = __builtin_amdgcn_mfma_f32_16x16x32_bf16(qf[1], k1f, sacc[nb], 0, 0, 0);
        }

        // scale + mask + online softmax
#pragma unroll
        for (int r = 0; r < 4; ++r) {
            int q = q0 + w * 16 + g * 4 + r;
            uint2 mb = *(const uint2*)&bits[((long long)b * SEQ + q) * (SEQ / 32) + (kv0 >> 5)];
            float sv[4];
#pragma unroll
            for (int nb = 0; nb < 4; ++nb) {
                unsigned word = (nb < 2) ? mb.x : mb.y;
                unsigned bit = (word >> ((nb & 1) * 16 + c)) & 1u;
                float s = sacc[nb][r] * 0.125f;
                sv[nb] = bit ? s : -1e9f;
            }
            float pmax = fmaxf(fmaxf(sv[0], sv[1]), fmaxf(sv[2], sv[3]));
#pragma unroll
            for (int off = 1; off < 16; off <<= 1)
                pmax = fmaxf(pmax, __shfl_xor(pmax, off));
            float mnew = fmaxf(m_run[r], pmax);
            float scale = __expf(m_run[r] - mnew);
            m_run[r] = mnew;
            float psum = 0.f;
#pragma unroll
            for (int nb = 0; nb < 4; ++nb) {
                float p = __expf(sv[nb] - mnew);
                sacc[nb][r] = p;
                psum += p;
            }
#pragma unroll
            for (int off = 1; off < 16; off <<= 1)
                psum += __shfl_xor(psum, off);
            l_run[r] = l_run[r] * scale + psum;
#pragma unroll
            for (int fb = 0; fb < 4; ++fb) o_acc[fb][r] *= scale;
        }

        // P -> LDS (per-wave region), transposing D-layout into A-fragment layout
#pragma unroll
        for (int nb = 0; nb < 4; ++nb)
#pragma unroll
            for (int r = 0; r < 4; ++r)
                Ps[w][g * 4 + r][nb * 16 + c] = (bf16)sacc[nb][r];
        __syncthreads();

        // O += P @ V
#pragma unroll
        for (int fb = 0; fb < 4; ++fb) {
#pragma unroll
            for (int kvb = 0; kvb < 2; ++kvb) {
                bf16x8 pf = *(const bf16x8*)&Ps[w][c][kvb * 32 + g * 8];
                bf16x8 vf = *(const bf16x8*)&Vs[fb * 16 + c][kvb * 32 + g * 8];
                o_acc[fb] = __builtin_amdgcn_mfma_f32_16x16x32_bf16(pf, vf, o_acc[fb], 0, 0, 0);
            }
        }
        __syncthreads();
    }

#pragma unroll
    for (int fb = 0; fb < 4; ++fb) {
#pragma unroll
        for (int r = 0; r < 4; ++r) {
            int q = q0 + w * 16 + g * 4 + r;
            float val = o_acc[fb][r] / l_run[r];
            O[((long long)b * SEQ + q) * D_MODEL + h * DH + fb * 16 + c] = (bf16)val;
        }
    }
}

// ---------------- launch ----------------
extern "C" void kernel_launch(void* const* d_in, const int* in_sizes, int n_in,
                              void* d_out, int out_size, void* d_ws, size_t ws_size,
                              hipStream_t stream) {
    const float* query = (const float*)d_in[0];
    const float* key_  = (const float*)d_in[1];
    const float* value = (const float*)d_in[2];
    const int*   mask  = (const int*)d_in[3];
    const float* Wq = (const float*)d_in[4];
    const float* bq = (const float*)d_in[5];
    const float* Wk = (const float*)d_in[6];
    const float* bk = (const float*)d_in[7];
    const float* Wv = (const float*)d_in[8];
    const float* bv = (const float*)d_in[9];
    const float* Wo = (const float*)d_in[10];
    const float* bo = (const float*)d_in[11];
    float* out = (float*)d_out;

    char* ws = (char*)d_ws;
    bf16* Q16  = (bf16*)(ws);                     // 16 MB  [B,H,S,DH]
    bf16* K16  = (bf16*)(ws + (16ll << 20));      // 16 MB  [B,H,S,DH]
    bf16* V16t = (bf16*)(ws + (32ll << 20));      // 16 MB  [B,H,DH,S]
    bf16* O16  = (bf16*)(ws + (48ll << 20));      // 16 MB  [B,S,D]
    bf16* WtQ  = (bf16*)(ws + (64ll << 20));      // 2 MB each
    bf16* WtK  = (bf16*)(ws + (66ll << 20));
    bf16* WtV  = (bf16*)(ws + (68ll << 20));
    bf16* WtO  = (bf16*)(ws + (70ll << 20));
    unsigned* bits = (unsigned*)(ws + (72ll << 20));  // 2 MB

    dim3 tb(32, 8), tg(32, 32);
    wt_kernel<<<tg, tb, 0, stream>>>(Wq, WtQ);
    wt_kernel<<<tg, tb, 0, stream>>>(Wk, WtK);
    wt_kernel<<<tg, tb, 0, stream>>>(Wv, WtV);
    wt_kernel<<<tg, tb, 0, stream>>>(Wo, WtO);

    maskpack_kernel<<<65536, 256, 0, stream>>>(mask, bits);

    dim3 gg(D_MODEL / 128, (BATCH * SEQ) / 128);  // (8, 64)
    gemm_kernel<false, 0><<<gg, 256, 0, stream>>>(query, WtQ, bq, Q16);
    gemm_kernel<false, 0><<<gg, 256, 0, stream>>>(key_,  WtK, bk, K16);
    gemm_kernel<false, 1><<<gg, 256, 0, stream>>>(value, WtV, bv, V16t);

    attn_kernel<<<dim3(SEQ / 64, BATCH * NHEAD), 256, 0, stream>>>(Q16, K16, V16t, bits, O16);

    gemm_kernel<true, 2><<<gg, 256, 0, stream>>>(O16, WtO, bo, out);
}

// Round 3
// 491.169 us; speedup vs baseline: 1.2514x; 1.2514x over previous
//
#include <hip/hip_runtime.h>
#include <hip/hip_bf16.h>
#include <stdint.h>

#define D_MODEL 1024
#define NHEAD   16
#define DH      64
#define BATCH   4
#define SEQ     2048

typedef __bf16 bf16;
typedef __bf16 bf16x8 __attribute__((ext_vector_type(8)));
typedef __bf16 bf16x4 __attribute__((ext_vector_type(4)));
typedef float  f32x4  __attribute__((ext_vector_type(4)));

__device__ __forceinline__ void gload16(const void* g, void* l) {
    __builtin_amdgcn_global_load_lds((const __attribute__((address_space(1))) uint32_t*)g,
                                     (__attribute__((address_space(3))) uint32_t*)l, 16, 0, 0);
}

// ---------------- weight transpose + convert: Wt[n][k] = (bf16) W[k][n] ----------------
__global__ __launch_bounds__(256) void wt_kernel(const float* __restrict__ W,
                                                 bf16* __restrict__ Wt) {
    __shared__ float t[32][33];
    int x = threadIdx.x, y = threadIdx.y;          // block (32,8)
    int bi = blockIdx.x * 32;                      // k rows
    int bj = blockIdx.y * 32;                      // n cols
#pragma unroll
    for (int j = 0; j < 4; ++j)
        t[y + j * 8][x] = W[(bi + y + j * 8) * D_MODEL + bj + x];
    __syncthreads();
#pragma unroll
    for (int j = 0; j < 4; ++j)
        Wt[(long long)(bj + y + j * 8) * D_MODEL + bi + x] = (bf16)t[x][y + j * 8];
}

// ---------------- fp32 -> bf16 convert (vectorized) ----------------
__global__ __launch_bounds__(256) void f2b_kernel(const float* __restrict__ in,
                                                  bf16* __restrict__ out) {
    long long i = ((long long)blockIdx.x * 256 + threadIdx.x) * 8;
    float4 a = *(const float4*)&in[i];
    float4 b = *(const float4*)&in[i + 4];
    bf16x8 o;
    o[0] = (bf16)a.x; o[1] = (bf16)a.y; o[2] = (bf16)a.z; o[3] = (bf16)a.w;
    o[4] = (bf16)b.x; o[5] = (bf16)b.y; o[6] = (bf16)b.z; o[7] = (bf16)b.w;
    *(bf16x8*)&out[i] = o;
}

// ---------------- mask pack: bits[b][q][kv/32], bit = (mask != 0) ----------------
__global__ __launch_bounds__(256) void maskpack_kernel(const int* __restrict__ mask,
                                                       unsigned* __restrict__ bits) {
    long long tid = (long long)blockIdx.x * 256 + threadIdx.x;
    int lane = threadIdx.x & 63;
    long long wid = tid >> 6;
    int m = mask[wid * 64 + lane];
    unsigned long long bal = __ballot(m != 0);
    if (lane == 0) *(unsigned long long*)&bits[wid * 2] = bal;
}

// ---------------- GEMM (m97 structure): C[M,N] = A[M,K] @ Bt[N,K]^T + bias ----------------
// OUT_MODE: 0 -> bf16 [B,H,S,Dh], 1 -> bf16 [B,H,Dh,S], 2 -> fp32 [M,N].
template <int OUT_MODE>
__global__ __launch_bounds__(256) void gemm_kernel(const bf16* __restrict__ A,
                                                   const bf16* __restrict__ Bt,
                                                   const float* __restrict__ bias,
                                                   void* __restrict__ Cptr) {
    constexpr int K = D_MODEL;
    __shared__ bf16 As[128][32];
    __shared__ bf16 Bs[128][32];
    int tid = threadIdx.x;
    int l = tid & 63, w = tid >> 6;
    int g = l >> 4, c = l & 15;
    int wm = (w >> 1) * 64, wn = (w & 1) * 64;
    long long m0 = (long long)blockIdx.y * 128;
    int n0 = blockIdx.x * 128;
    int srow = l >> 2, scolb = (l & 3) * 16;

    f32x4 acc[4][4] = {};

    for (int k0 = 0; k0 < K; k0 += 32) {
#pragma unroll
        for (int i = 0; i < 2; ++i) {
            int ck = w * 2 + i;
            int row = ck * 16 + srow;
            gload16((const char*)(A + (m0 + row) * K + k0) + scolb,
                    (char*)&As[0][0] + ck * 1024);
            gload16((const char*)(Bt + (long long)(n0 + row) * K + k0) + scolb,
                    (char*)&Bs[0][0] + ck * 1024);
        }
        __syncthreads();
        bf16x8 af[4], bfr[4];
#pragma unroll
        for (int i = 0; i < 4; ++i) af[i] = *(const bf16x8*)&As[wm + i * 16 + c][g * 8];
#pragma unroll
        for (int i = 0; i < 4; ++i) bfr[i] = *(const bf16x8*)&Bs[wn + i * 16 + c][g * 8];
#pragma unroll
        for (int mi = 0; mi < 4; ++mi)
#pragma unroll
            for (int ni = 0; ni < 4; ++ni)
                acc[mi][ni] = __builtin_amdgcn_mfma_f32_16x16x32_bf16(af[mi], bfr[ni],
                                                                     acc[mi][ni], 0, 0, 0);
        __syncthreads();
    }

#pragma unroll
    for (int mi = 0; mi < 4; ++mi) {
#pragma unroll
        for (int ni = 0; ni < 4; ++ni) {
            int n = n0 + wn + ni * 16 + c;
            float bv = bias[n];
#pragma unroll
            for (int r = 0; r < 4; ++r) {
                long long m = m0 + wm + mi * 16 + g * 4 + r;
                float val = acc[mi][ni][r] + bv;
                if constexpr (OUT_MODE == 2) {
                    ((float*)Cptr)[m * D_MODEL + n] = val;
                } else {
                    int b = (int)(m >> 11), s = (int)(m & 2047);
                    int h = n >> 6, f = n & 63;
                    long long addr;
                    if constexpr (OUT_MODE == 0)
                        addr = ((long long)(b * NHEAD + h) * SEQ + s) * DH + f;
                    else
                        addr = ((long long)(b * NHEAD + h) * DH + f) * SEQ + s;
                    ((bf16*)Cptr)[addr] = (bf16)val;
                }
            }
        }
    }
}

// ---------------- flash attention (swapped QK^T, lane-local softmax) ----------------
// Q,Kt: [BH][S][DH] bf16; Vt: [BH][DH][S] bf16; bits: packed mask; O: [B][S][D_MODEL] bf16
__global__ __launch_bounds__(256) void attn_kernel(const bf16* __restrict__ Q,
                                                   const bf16* __restrict__ Kt,
                                                   const bf16* __restrict__ Vt,
                                                   const unsigned* __restrict__ bits,
                                                   bf16* __restrict__ O) {
    __shared__ bf16 Ks[2][64][64];   // XOR-swizzled: content(row, colb) = K[row][colb ^ ((row&7)<<4)]
    __shared__ bf16 Vs[2][64][64];   // same swizzle, rows = dh
    __shared__ bf16 Ps[4][16][64];   // per-wave private, same swizzle
    int tid = threadIdx.x;
    int l = tid & 63, w = tid >> 6;
    int g = l >> 4, c = l & 15;
    int bh = blockIdx.y;
    int b = bh >> 4, h = bh & 15;
    int q0 = blockIdx.x * 64;
    int q = q0 + w * 16 + c;          // this lane's softmax row

    const long long kbase = (long long)bh * SEQ * DH;
    const long long vbase = (long long)bh * DH * SEQ;

    bf16x8 qf0, qf1;
    {
        long long base = ((long long)bh * SEQ + q) * DH + g * 8;
        qf0 = *(const bf16x8*)&Q[base];
        qf1 = *(const bf16x8*)&Q[base + 32];
    }

    int srow = l >> 3;                   // 0..7
    int scolb = ((l & 7) ^ srow) * 16;   // pre-swizzled source byte-col

    f32x4 o_acc[4] = {};
    float m_run = -INFINITY, l_run = 0.f;
    const unsigned* mrow = &bits[((long long)b * SEQ + q) * (SEQ / 32)];
    int gx8 = (g ^ (c & 7)) * 8;
    int pswz = (c & 7) * 8;

    auto stage = [&](int buf, int kv0) {
#pragma unroll
        for (int i = 0; i < 2; ++i) {
            int ck = w * 2 + i;
            int row = ck * 8 + srow;
            gload16((const char*)(Kt + kbase + (long long)(kv0 + row) * DH) + scolb,
                    (char*)&Ks[buf][0][0] + ck * 1024);
            gload16((const char*)(Vt + vbase + (long long)row * SEQ + kv0) + scolb,
                    (char*)&Vs[buf][0][0] + ck * 1024);
        }
    };
    stage(0, 0);

    int cur = 0;
    for (int t = 0; t < SEQ / 64; ++t) {
        __syncthreads();                 // stage(cur) done (vmcnt drained); prev reads of cur^1 done
        if (t + 1 < SEQ / 64) stage(cur ^ 1, (t + 1) * 64);

        // ---- S^T = K Q^T : lane holds S[kv = nb*16 + g*4 + r][q = c] ----
        f32x4 sacc[4] = {};
#pragma unroll
        for (int nb = 0; nb < 4; ++nb) {
            bf16x8 k0f = *(const bf16x8*)&Ks[cur][nb * 16 + c][gx8];
            bf16x8 k1f = *(const bf16x8*)&Ks[cur][nb * 16 + c][gx8 ^ 32];
            sacc[nb] = __builtin_amdgcn_mfma_f32_16x16x32_bf16(k0f, qf0, sacc[nb], 0, 0, 0);
            sacc[nb] = __builtin_amdgcn_mfma_f32_16x16x32_bf16(k1f, qf1, sacc[nb], 0, 0, 0);
        }

        // ---- mask + scale + lane-local max ----
        uint2 mb = *(const uint2*)&mrow[t * 2];
        unsigned wsel[4] = { mb.x >> (g * 4), mb.x >> (16 + g * 4),
                             mb.y >> (g * 4), mb.y >> (16 + g * 4) };
        float pmax = -INFINITY;
#pragma unroll
        for (int nb = 0; nb < 4; ++nb)
#pragma unroll
            for (int r = 0; r < 4; ++r) {
                float s = sacc[nb][r] * 0.125f;
                s = ((wsel[nb] >> r) & 1u) ? s : -1e9f;
                sacc[nb][r] = s;
                pmax = fmaxf(pmax, s);
            }
        pmax = fmaxf(pmax, __shfl_xor(pmax, 16));
        pmax = fmaxf(pmax, __shfl_xor(pmax, 32));

        // ---- defer-max (THR=8) rescale ----
        if (__any(pmax > m_run + 8.f)) {
            float mnew = fmaxf(m_run, pmax);
            float sc_own = __expf(m_run - mnew);
            m_run = mnew;
            l_run *= sc_own;
#pragma unroll
            for (int r = 0; r < 4; ++r) {
                float sc = __shfl(sc_own, g * 4 + r);
#pragma unroll
                for (int fb = 0; fb < 4; ++fb) o_acc[fb][r] *= sc;
            }
        }

        // ---- exp + P write (b64, swizzled) + row-sum ----
        float tsum = 0.f;
#pragma unroll
        for (int nb = 0; nb < 4; ++nb) {
            bf16x4 pk;
#pragma unroll
            for (int r = 0; r < 4; ++r) {
                float p = __expf(sacc[nb][r] - m_run);
                tsum += p;
                pk[r] = (bf16)p;
            }
            *(bf16x4*)&Ps[w][c][(nb * 16 + g * 4) ^ pswz] = pk;
        }
        tsum += __shfl_xor(tsum, 16);
        tsum += __shfl_xor(tsum, 32);
        l_run += tsum;

        // ---- O += P V ----
#pragma unroll
        for (int kvb = 0; kvb < 2; ++kvb) {
            bf16x8 pf = *(const bf16x8*)&Ps[w][c][((kvb * 4 + g) ^ (c & 7)) * 8];
#pragma unroll
            for (int fb = 0; fb < 4; ++fb) {
                bf16x8 vf = *(const bf16x8*)&Vs[cur][fb * 16 + c][((kvb * 4 + g) ^ (c & 7)) * 8];
                o_acc[fb] = __builtin_amdgcn_mfma_f32_16x16x32_bf16(pf, vf, o_acc[fb], 0, 0, 0);
            }
        }
        cur ^= 1;
    }

    float linv[4];
#pragma unroll
    for (int r = 0; r < 4; ++r) linv[r] = 1.0f / __shfl(l_run, g * 4 + r);
#pragma unroll
    for (int fb = 0; fb < 4; ++fb)
#pragma unroll
        for (int r = 0; r < 4; ++r) {
            int qq = q0 + w * 16 + g * 4 + r;
            O[((long long)b * SEQ + qq) * D_MODEL + h * DH + fb * 16 + c] =
                (bf16)(o_acc[fb][r] * linv[r]);
        }
}

// ---------------- launch ----------------
extern "C" void kernel_launch(void* const* d_in, const int* in_sizes, int n_in,
                              void* d_out, int out_size, void* d_ws, size_t ws_size,
                              hipStream_t stream) {
    const float* query = (const float*)d_in[0];
    const float* key_  = (const float*)d_in[1];
    const float* value = (const float*)d_in[2];
    const int*   mask  = (const int*)d_in[3];
    const float* Wq = (const float*)d_in[4];
    const float* bq = (const float*)d_in[5];
    const float* Wk = (const float*)d_in[6];
    const float* bk = (const float*)d_in[7];
    const float* Wv = (const float*)d_in[8];
    const float* bv = (const float*)d_in[9];
    const float* Wo = (const float*)d_in[10];
    const float* bo = (const float*)d_in[11];
    float* out = (float*)d_out;

    char* ws = (char*)d_ws;
    bf16* Q16  = (bf16*)(ws);                     // 16 MB  [B,H,S,DH]
    bf16* K16  = (bf16*)(ws + (16ll << 20));      // 16 MB  [B,H,S,DH]
    bf16* V16t = (bf16*)(ws + (32ll << 20));      // 16 MB  [B,H,Dh,S]
    bf16* O16  = (bf16*)(ws + (48ll << 20));      // 16 MB  [B,S,D]
    bf16* WtQ  = (bf16*)(ws + (64ll << 20));      // 2 MB each
    bf16* WtK  = (bf16*)(ws + (66ll << 20));
    bf16* WtV  = (bf16*)(ws + (68ll << 20));
    bf16* WtO  = (bf16*)(ws + (70ll << 20));
    unsigned* bits = (unsigned*)(ws + (72ll << 20));  // 2 MB
    bf16* Qb = (bf16*)(ws + (76ll << 20));        // 16 MB each, bf16 activations
    bf16* Kb = (bf16*)(ws + (92ll << 20));
    bf16* Vb = (bf16*)(ws + (108ll << 20));

    dim3 tb(32, 8), tg(32, 32);
    wt_kernel<<<tg, tb, 0, stream>>>(Wq, WtQ);
    wt_kernel<<<tg, tb, 0, stream>>>(Wk, WtK);
    wt_kernel<<<tg, tb, 0, stream>>>(Wv, WtV);
    wt_kernel<<<tg, tb, 0, stream>>>(Wo, WtO);

    maskpack_kernel<<<65536, 256, 0, stream>>>(mask, bits);

    f2b_kernel<<<4096, 256, 0, stream>>>(query, Qb);
    f2b_kernel<<<4096, 256, 0, stream>>>(key_,  Kb);
    f2b_kernel<<<4096, 256, 0, stream>>>(value, Vb);

    dim3 gg(D_MODEL / 128, (BATCH * SEQ) / 128);  // (8, 64)
    gemm_kernel<0><<<gg, 256, 0, stream>>>(Qb, WtQ, bq, Q16);
    gemm_kernel<0><<<gg, 256, 0, stream>>>(Kb, WtK, bk, K16);
    gemm_kernel<1><<<gg, 256, 0, stream>>>(Vb, WtV, bv, V16t);

    attn_kernel<<<dim3(SEQ / 64, BATCH * NHEAD), 256, 0, stream>>>(Q16, K16, V16t, bits, O16);

    gemm_kernel<2><<<gg, 256, 0, stream>>>(O16, WtO, bo, out);
}

// Round 6
// 466.285 us; speedup vs baseline: 1.3182x; 1.0534x over previous
//
#include <hip/hip_runtime.h>
#include <hip/hip_bf16.h>
#include <stdint.h>

#define D_MODEL 1024
#define NHEAD   16
#define DH      64
#define BATCH   4
#define SEQ     2048

typedef __bf16 bf16;
typedef __bf16 bf16x8 __attribute__((ext_vector_type(8)));
typedef __bf16 bf16x4 __attribute__((ext_vector_type(4)));
typedef float  f32x4  __attribute__((ext_vector_type(4)));

__device__ __forceinline__ void gload16(const void* g, void* l) {
    __builtin_amdgcn_global_load_lds((const __attribute__((address_space(1))) uint32_t*)g,
                                     (__attribute__((address_space(3))) uint32_t*)l, 16, 0, 0);
}

// ---------------- weight transpose + convert: Wt[n][k] = (bf16) W[k][n] ----------------
__global__ __launch_bounds__(256) void wt_kernel(const float* __restrict__ W,
                                                 bf16* __restrict__ Wt) {
    __shared__ float t[32][33];
    int x = threadIdx.x, y = threadIdx.y;          // block (32,8)
    int bi = blockIdx.x * 32;                      // k rows
    int bj = blockIdx.y * 32;                      // n cols
#pragma unroll
    for (int j = 0; j < 4; ++j)
        t[y + j * 8][x] = W[(bi + y + j * 8) * D_MODEL + bj + x];
    __syncthreads();
#pragma unroll
    for (int j = 0; j < 4; ++j)
        Wt[(long long)(bj + y + j * 8) * D_MODEL + bi + x] = (bf16)t[x][y + j * 8];
}

// ---------------- fp32 -> bf16 convert, 3 inputs -> contiguous A3 ----------------
__global__ __launch_bounds__(256) void f2b3_kernel(const float* __restrict__ q,
                                                   const float* __restrict__ k,
                                                   const float* __restrict__ v,
                                                   bf16* __restrict__ out) {
    int third = blockIdx.x >> 12;                  // 4096 blocks per input
    int wi = blockIdx.x & 4095;
    const float* in = third == 0 ? q : (third == 1 ? k : v);
    long long i = (long long)wi * 2048 + threadIdx.x * 8;
    float4 a = *(const float4*)&in[i];
    float4 b = *(const float4*)&in[i + 4];
    bf16x8 o;
    o[0] = (bf16)a.x; o[1] = (bf16)a.y; o[2] = (bf16)a.z; o[3] = (bf16)a.w;
    o[4] = (bf16)b.x; o[5] = (bf16)b.y; o[6] = (bf16)b.z; o[7] = (bf16)b.w;
    *(bf16x8*)&out[(long long)third * (8192ll * 1024) + i] = o;
}

// ---------------- mask pack: bits[b][q][kv/32], bit = (mask != 0) ----------------
__global__ __launch_bounds__(256) void maskpack_kernel(const int* __restrict__ mask,
                                                       unsigned* __restrict__ bits) {
    long long tid = (long long)blockIdx.x * 256 + threadIdx.x;
    int lane = threadIdx.x & 63;
    long long wid = tid >> 6;
    int m = mask[wid * 64 + lane];
    unsigned long long bal = __ballot(m != 0);
    if (lane == 0) *(unsigned long long*)&bits[wid * 2] = bal;
}

// ---------------- fused QKV GEMM: third = blockIdx.y>>6 selects {Q,K,V} ----------------
// A3: [3][8192][1024] bf16; Wt3: [3][1024][1024] bf16 (row n = weight col);
// out3: [3][B,H,S,Dh] bf16. Q third scaled by 0.125.
__global__ __launch_bounds__(256) void gemm_qkv_kernel(const bf16* __restrict__ A3,
                                                       const bf16* __restrict__ Wt3,
                                                       const float* __restrict__ bq,
                                                       const float* __restrict__ bk,
                                                       const float* __restrict__ bv,
                                                       bf16* __restrict__ out3) {
    constexpr int K = D_MODEL;
    __shared__ bf16 As[128][32];
    __shared__ bf16 Bs[128][32];
    int tid = threadIdx.x;
    int l = tid & 63, w = tid >> 6;
    int g = l >> 4, c = l & 15;
    int wm = (w >> 1) * 64, wn = (w & 1) * 64;
    int third = blockIdx.y >> 6;
    long long m0 = (long long)(blockIdx.y & 63) * 128;
    int n0 = blockIdx.x * 128;
    const bf16* A  = A3  + (long long)third * (8192ll * 1024);
    const bf16* Bt = Wt3 + (long long)third * (1024ll * 1024);
    const float* bias = third == 0 ? bq : (third == 1 ? bk : bv);
    float osc = third == 0 ? 0.125f : 1.0f;
    bf16* C = out3 + (long long)third * (8192ll * 1024);
    int srow = l >> 2, scolb = (l & 3) * 16;

    f32x4 acc[4][4] = {};

    for (int k0 = 0; k0 < K; k0 += 32) {
#pragma unroll
        for (int i = 0; i < 2; ++i) {
            int ck = w * 2 + i;
            int row = ck * 16 + srow;
            gload16((const char*)(A + (m0 + row) * K + k0) + scolb,
                    (char*)&As[0][0] + ck * 1024);
            gload16((const char*)(Bt + (long long)(n0 + row) * K + k0) + scolb,
                    (char*)&Bs[0][0] + ck * 1024);
        }
        __syncthreads();
        bf16x8 af[4], bfr[4];
#pragma unroll
        for (int i = 0; i < 4; ++i) af[i] = *(const bf16x8*)&As[wm + i * 16 + c][g * 8];
#pragma unroll
        for (int i = 0; i < 4; ++i) bfr[i] = *(const bf16x8*)&Bs[wn + i * 16 + c][g * 8];
#pragma unroll
        for (int mi = 0; mi < 4; ++mi)
#pragma unroll
            for (int ni = 0; ni < 4; ++ni)
                acc[mi][ni] = __builtin_amdgcn_mfma_f32_16x16x32_bf16(af[mi], bfr[ni],
                                                                     acc[mi][ni], 0, 0, 0);
        __syncthreads();
    }

#pragma unroll
    for (int mi = 0; mi < 4; ++mi) {
#pragma unroll
        for (int ni = 0; ni < 4; ++ni) {
            int n = n0 + wn + ni * 16 + c;
            float bv_ = bias[n];
            int h = n >> 6, f = n & 63;
#pragma unroll
            for (int r = 0; r < 4; ++r) {
                long long m = m0 + wm + mi * 16 + g * 4 + r;
                float val = (acc[mi][ni][r] + bv_) * osc;
                int b = (int)(m >> 11), s = (int)(m & 2047);
                C[((long long)(b * NHEAD + h) * SEQ + s) * DH + f] = (bf16)val;
            }
        }
    }
}

// ---------------- O-projection GEMM: out[M,N] fp32 = O16[M,K] @ WtO^T + bo ----------------
__global__ __launch_bounds__(256) void gemm_out_kernel(const bf16* __restrict__ A,
                                                       const bf16* __restrict__ Bt,
                                                       const float* __restrict__ bias,
                                                       float* __restrict__ Cptr) {
    constexpr int K = D_MODEL;
    __shared__ bf16 As[128][32];
    __shared__ bf16 Bs[128][32];
    int tid = threadIdx.x;
    int l = tid & 63, w = tid >> 6;
    int g = l >> 4, c = l & 15;
    int wm = (w >> 1) * 64, wn = (w & 1) * 64;
    long long m0 = (long long)blockIdx.y * 128;
    int n0 = blockIdx.x * 128;
    int srow = l >> 2, scolb = (l & 3) * 16;

    f32x4 acc[4][4] = {};

    for (int k0 = 0; k0 < K; k0 += 32) {
#pragma unroll
        for (int i = 0; i < 2; ++i) {
            int ck = w * 2 + i;
            int row = ck * 16 + srow;
            gload16((const char*)(A + (m0 + row) * K + k0) + scolb,
                    (char*)&As[0][0] + ck * 1024);
            gload16((const char*)(Bt + (long long)(n0 + row) * K + k0) + scolb,
                    (char*)&Bs[0][0] + ck * 1024);
        }
        __syncthreads();
        bf16x8 af[4], bfr[4];
#pragma unroll
        for (int i = 0; i < 4; ++i) af[i] = *(const bf16x8*)&As[wm + i * 16 + c][g * 8];
#pragma unroll
        for (int i = 0; i < 4; ++i) bfr[i] = *(const bf16x8*)&Bs[wn + i * 16 + c][g * 8];
#pragma unroll
        for (int mi = 0; mi < 4; ++mi)
#pragma unroll
            for (int ni = 0; ni < 4; ++ni)
                acc[mi][ni] = __builtin_amdgcn_mfma_f32_16x16x32_bf16(af[mi], bfr[ni],
                                                                     acc[mi][ni], 0, 0, 0);
        __syncthreads();
    }

#pragma unroll
    for (int mi = 0; mi < 4; ++mi)
#pragma unroll
        for (int ni = 0; ni < 4; ++ni) {
            int n = n0 + wn + ni * 16 + c;
            float bv = bias[n];
#pragma unroll
            for (int r = 0; r < 4; ++r) {
                long long m = m0 + wm + mi * 16 + g * 4 + r;
                Cptr[m * D_MODEL + n] = acc[mi][ni][r] + bv;
            }
        }
}

// ---------------- V transpose: [B,H,S,Dh] -> [B,H,Dh,S] (LDS-tiled, coalesced) -------------
__global__ __launch_bounds__(256) void vtrans_kernel(const bf16* __restrict__ in,
                                                     bf16* __restrict__ out) {
    __shared__ bf16 t[64][72];
    int bh = blockIdx.y;
    int s0 = blockIdx.x * 64;
    int tid = threadIdx.x;
#pragma unroll
    for (int i = 0; i < 2; ++i) {
        int ck = tid + i * 256;
        int s = ck >> 3, f0 = (ck & 7) * 8;
        bf16x8 v = *(const bf16x8*)&in[((long long)bh * SEQ + s0 + s) * DH + f0];
#pragma unroll
        for (int j = 0; j < 8; ++j) t[f0 + j][s] = v[j];
    }
    __syncthreads();
#pragma unroll
    for (int i = 0; i < 2; ++i) {
        int ck = tid + i * 256;
        int f = ck >> 3, c0 = (ck & 7) * 8;
        bf16x8 v = *(const bf16x8*)&t[f][c0];
        *(bf16x8*)&out[((long long)bh * DH + f) * SEQ + s0 + c0] = v;
    }
}

// ---------------- flash attention: 8 waves, 128 q-rows/block ----------------
// Q pre-scaled by 0.125. Q,Kt: [BH][S][DH]; Vt: [BH][DH][S]; O: [B][S][D] bf16
__global__ __launch_bounds__(512) void attn_kernel(const bf16* __restrict__ Q,
                                                   const bf16* __restrict__ Kt,
                                                   const bf16* __restrict__ Vt,
                                                   const unsigned* __restrict__ bits,
                                                   bf16* __restrict__ O) {
    __shared__ bf16 Ks[2][64][64];   // content(row, colchunk u) = K[row][(u^(row&7))*8..]
    __shared__ bf16 Vs[2][64][64];
    __shared__ bf16 Ps[8][16][64];
    int tid = threadIdx.x;
    int l = tid & 63, w = tid >> 6;          // w 0..7
    int g = l >> 4, c = l & 15;
    // XCD-chunked swizzle: each XCD owns 128 consecutive logical blocks (= 8 heads)
    int orig = blockIdx.x;                    // 1024 blocks
    int swz = (orig & 7) * 128 + (orig >> 3);
    int bh = swz >> 4, qb = swz & 15;
    int b = bh >> 4, h = bh & 15;
    int q0 = qb * 128;
    int q = q0 + w * 16 + c;                  // this lane's softmax row

    const long long kbase = (long long)bh * SEQ * DH;
    const long long vbase = (long long)bh * DH * SEQ;

    bf16x8 qf0, qf1;
    {
        long long base = ((long long)bh * SEQ + q) * DH + g * 8;
        qf0 = *(const bf16x8*)&Q[base];
        qf1 = *(const bf16x8*)&Q[base + 32];
    }

    int row = tid >> 3;                        // 0..63 staging row
    int scolb = ((tid & 7) ^ (row & 7)) * 16;  // pre-swizzled source byte-col

    f32x4 o_acc[4] = {};
    float m_run = -INFINITY, l_run = 0.f;
    const unsigned* mrow = &bits[((long long)b * SEQ + q) * (SEQ / 32)];
    int gx8 = (g ^ (c & 7)) * 8;

    auto stage = [&](int buf, int kv0) {
        gload16((const char*)(Kt + kbase + (long long)(kv0 + row) * DH) + scolb,
                (char*)&Ks[buf][0][0] + w * 1024);
        gload16((const char*)(Vt + vbase + (long long)row * SEQ + kv0) + scolb,
                (char*)&Vs[buf][0][0] + w * 1024);
    };
    stage(0, 0);

    int cur = 0;
    for (int t = 0; t < SEQ / 64; ++t) {
        __syncthreads();                 // stage(cur) drained; prior reads of cur^1 done
        if (t + 1 < SEQ / 64) stage(cur ^ 1, (t + 1) * 64);

        // ---- S^T = K Q^T : lane holds S[kv = nb*16 + g*4 + r][q = c] (pre-scaled) ----
        f32x4 sacc[4] = {};
#pragma unroll
        for (int nb = 0; nb < 4; ++nb) {
            bf16x8 k0f = *(const bf16x8*)&Ks[cur][nb * 16 + c][gx8];
            bf16x8 k1f = *(const bf16x8*)&Ks[cur][nb * 16 + c][gx8 ^ 32];
            sacc[nb] = __builtin_amdgcn_mfma_f32_16x16x32_bf16(k0f, qf0, sacc[nb], 0, 0, 0);
            sacc[nb] = __builtin_amdgcn_mfma_f32_16x16x32_bf16(k1f, qf1, sacc[nb], 0, 0, 0);
        }

        // ---- unmasked max (ratios exact; avoids per-element mask before max) ----
        float pmax = sacc[0][0];
#pragma unroll
        for (int nb = 0; nb < 4; ++nb)
#pragma unroll
            for (int r = 0; r < 4; ++r) pmax = fmaxf(pmax, sacc[nb][r]);
        pmax = fmaxf(pmax, __shfl_xor(pmax, 16));
        pmax = fmaxf(pmax, __shfl_xor(pmax, 32));

        // ---- defer-max (THR=8) rescale ----
        if (__any(pmax > m_run + 8.f)) {
            float mnew = fmaxf(m_run, pmax);
            float sc_own = __expf(m_run - mnew);
            m_run = mnew;
            l_run *= sc_own;
#pragma unroll
            for (int r = 0; r < 4; ++r) {
                float sc = __shfl(sc_own, g * 4 + r);
#pragma unroll
                for (int fb = 0; fb < 4; ++fb) o_acc[fb][r] *= sc;
            }
        }

        // ---- exp, mask after exp, P write (b64, swizzled), row-sum ----
        uint2 mb = *(const uint2*)&mrow[t * 2];
        unsigned wsel[4] = { mb.x >> (g * 4), mb.x >> (16 + g * 4),
                             mb.y >> (g * 4), mb.y >> (16 + g * 4) };
        float tsum = 0.f;
#pragma unroll
        for (int nb = 0; nb < 4; ++nb) {
            bf16x4 pk;
#pragma unroll
            for (int r = 0; r < 4; ++r) {
                float p = __expf(sacc[nb][r] - m_run);
                p = ((wsel[nb] >> r) & 1u) ? p : 0.f;
                tsum += p;
                pk[r] = (bf16)p;
            }
            *(bf16x4*)&Ps[w][c][(nb * 16 + g * 4) ^ ((c & 7) * 8)] = pk;
        }
        tsum += __shfl_xor(tsum, 16);
        tsum += __shfl_xor(tsum, 32);
        l_run += tsum;

        // ---- O += P V ----
#pragma unroll
        for (int kvb = 0; kvb < 2; ++kvb) {
            bf16x8 pf = *(const bf16x8*)&Ps[w][c][((kvb * 4 + g) ^ (c & 7)) * 8];
#pragma unroll
            for (int fb = 0; fb < 4; ++fb) {
                bf16x8 vf = *(const bf16x8*)&Vs[cur][fb * 16 + c][((kvb * 4 + g) ^ (c & 7)) * 8];
                o_acc[fb] = __builtin_amdgcn_mfma_f32_16x16x32_bf16(pf, vf, o_acc[fb], 0, 0, 0);
            }
        }
        cur ^= 1;
    }

    float linv[4];
#pragma unroll
    for (int r = 0; r < 4; ++r) linv[r] = 1.0f / __shfl(l_run, g * 4 + r);
#pragma unroll
    for (int fb = 0; fb < 4; ++fb)
#pragma unroll
        for (int r = 0; r < 4; ++r) {
            int qq = q0 + w * 16 + g * 4 + r;
            O[((long long)b * SEQ + qq) * D_MODEL + h * DH + fb * 16 + c] =
                (bf16)(o_acc[fb][r] * linv[r]);
        }
}

// ---------------- launch ----------------
extern "C" void kernel_launch(void* const* d_in, const int* in_sizes, int n_in,
                              void* d_out, int out_size, void* d_ws, size_t ws_size,
                              hipStream_t stream) {
    const float* query = (const float*)d_in[0];
    const float* key_  = (const float*)d_in[1];
    const float* value = (const float*)d_in[2];
    const int*   mask  = (const int*)d_in[3];
    const float* Wq = (const float*)d_in[4];
    const float* bq = (const float*)d_in[5];
    const float* Wk = (const float*)d_in[6];
    const float* bk = (const float*)d_in[7];
    const float* Wv = (const float*)d_in[8];
    const float* bv = (const float*)d_in[9];
    const float* Wo = (const float*)d_in[10];
    const float* bo = (const float*)d_in[11];
    float* out = (float*)d_out;

    char* ws = (char*)d_ws;
    bf16* A3    = (bf16*)(ws);                    // 48 MB [3][8192][1024] (dead after qkv gemm)
    bf16* V16t  = (bf16*)(ws);                    // 16 MB (aliases A3[0:16], after gemm)
    bf16* O16   = (bf16*)(ws + (16ll << 20));     // 16 MB (aliases A3[16:32], after vtrans)
    bf16* Q16   = (bf16*)(ws + (48ll << 20));     // 16 MB [B,H,S,Dh] (pre-scaled 0.125)
    bf16* K16   = (bf16*)(ws + (64ll << 20));     // 16 MB [B,H,S,Dh]
    bf16* V16   = (bf16*)(ws + (80ll << 20));     // 16 MB [B,H,S,Dh]
    bf16* Wt3   = (bf16*)(ws + (96ll << 20));     // 6 MB [3][1024][1024]
    bf16* WtO   = (bf16*)(ws + (102ll << 20));    // 2 MB
    unsigned* bits = (unsigned*)(ws + (104ll << 20));  // 2 MB

    dim3 tb(32, 8), tg(32, 32);
    wt_kernel<<<tg, tb, 0, stream>>>(Wq, Wt3);
    wt_kernel<<<tg, tb, 0, stream>>>(Wk, Wt3 + 1024ll * 1024);
    wt_kernel<<<tg, tb, 0, stream>>>(Wv, Wt3 + 2048ll * 1024);
    wt_kernel<<<tg, tb, 0, stream>>>(Wo, WtO);

    maskpack_kernel<<<65536, 256, 0, stream>>>(mask, bits);

    f2b3_kernel<<<12288, 256, 0, stream>>>(query, key_, value, A3);

    gemm_qkv_kernel<<<dim3(8, 192), 256, 0, stream>>>(A3, Wt3, bq, bk, bv, Q16);

    vtrans_kernel<<<dim3(32, 64), 256, 0, stream>>>(V16, V16t);

    attn_kernel<<<1024, 512, 0, stream>>>(Q16, K16, V16t, bits, O16);

    gemm_out_kernel<<<dim3(8, 64), 256, 0, stream>>>(O16, WtO, bo, out);
}